// Round 1
// baseline (169.445 us; speedup 1.0000x reference)
//
#include <hip/hip_runtime.h>

// ONN conv2d: B=16, Cin=128, H=W=32, Cout=256, k=3 (pad=1, stride=1)
// N=16384 positions, D=1152=18*64 chunks of VEC=64, M=256.
// out[n,m] = sum_r sign01( dot_c( x[n,64r+c], wq[64r+c,m] ) )
// wq = clamp(rintf(w*scale), -7, 7), scale = fl32(15/(fl32(max-min)+1e-9f))
//
// Main path: bf16 MFMA with x split hi/lo (w int4 exact in bf16).
// |mfma_dot - ref_fp32_chain| < ~2e-3; dots with |s| < TAU=0.03 recomputed
// bit-exactly (sequential fp32, ascending c, separate mul/add -- R4 body).
// R3->R4: per-dot global atomics -> per-block LDS queue (611 -> 93 us).
// R5 FAILED: rewritten k_fix body flipped a sign; reverted (proven R4 body).
// R6: k_fix grid 64->512. R7: barrier-free gather k_main.
// R8: depth-1 B prefetch + k_fix folded into k_main tail (64 us k_main;
//     MfmaUtil 11.5 / VALUBusy 41.6 / Occupancy 30 -- 47% idle-stall).
// R9: (a) split-K z=2 (9 chunks/block, 1024->2048 blocks, occupancy cap
//     16->32 waves/CU); out pre-zeroed in k_prep, epilogue atomicAdd
//     (integer-valued f32 adds: exact, order-independent);
//     (b) rolling depth-1 A-fragment prefetch across mt (A L2 latency was
//     unhidden: loads sat adjacent to consuming MFMAs at VGPR=56);
//     (c) ds_read_b128 offset fetch + v_perm_b32 hi/lo repack (VALU trim);
//     (d) __launch_bounds__(256,6) so regalloc can hold the prefetch regs.

#define TAU 0.03f
#define HITCAP 2048

typedef short short8 __attribute__((ext_vector_type(8)));
typedef float f32x4 __attribute__((ext_vector_type(4)));
typedef unsigned int uv4 __attribute__((ext_vector_type(4)));

__device__ __forceinline__ unsigned short bf16rn(float v) {
    unsigned u = __float_as_uint(v);
    unsigned r = u + 0x7fffu + ((u >> 16) & 1u);
    return (unsigned short)(r >> 16);
}

// ---------------- prep: weight min/max partials (blocks 0..63) +
//   zero-padded hi/lo bf16 planes (blocks 64..2111) +
//   out zero-fill (blocks 2112..4159; split-K epilogue is atomicAdd) --------
__global__ __launch_bounds__(256) void k_prep(const float* __restrict__ w,
                                              const float* __restrict__ inp,
                                              float* __restrict__ pmin,
                                              float* __restrict__ pmax,
                                              unsigned* __restrict__ xpk,
                                              float* __restrict__ out) {
    if (blockIdx.x < 64) {
        int tid = blockIdx.x * 256 + threadIdx.x;
        float vmin = 1e30f, vmax = -1e30f;
        for (int i = tid; i < 294912; i += 64 * 256) {
            float v = w[i];
            vmin = fminf(vmin, v);
            vmax = fmaxf(vmax, v);
        }
        #pragma unroll
        for (int off = 32; off > 0; off >>= 1) {
            vmin = fminf(vmin, __shfl_down(vmin, off, 64));
            vmax = fmaxf(vmax, __shfl_down(vmax, off, 64));
        }
        __shared__ float smin[4], smax[4];
        int wave = threadIdx.x >> 6;
        if ((threadIdx.x & 63) == 0) { smin[wave] = vmin; smax[wave] = vmax; }
        __syncthreads();
        if (threadIdx.x == 0) {
            #pragma unroll
            for (int i = 1; i < 4; i++) {
                vmin = fminf(vmin, smin[i]);
                vmax = fmaxf(vmax, smax[i]);
            }
            pmin[blockIdx.x] = vmin;
            pmax[blockIdx.x] = vmax;
        }
    } else if (blockIdx.x < 2112) {
        int bc = blockIdx.x - 64;              // b*128 + cin (2048)
        const float* src = inp + (size_t)bc * 1024;
        unsigned* dst = xpk + (size_t)bc * 1156;
        #pragma unroll
        for (int i = 0; i < 5; ++i) {
            int idx = threadIdx.x + i * 256;
            if (idx < 1156) {
                int yy = idx / 34, xx = idx - yy * 34;
                float v = 0.0f;
                int ys = yy - 1, xs_ = xx - 1;
                if ((unsigned)ys < 32u && (unsigned)xs_ < 32u) v = src[ys * 32 + xs_];
                unsigned short h = bf16rn(v);
                float hf = __uint_as_float((unsigned)h << 16);
                unsigned short l = bf16rn(v - hf);
                dst[idx] = (unsigned)h | ((unsigned)l << 16);
            }
        }
    } else {
        // zero out[16,256,32,32]: 1,048,576 float4 over 2048 blocks
        int zb = blockIdx.x - 2112;
        float4* o4 = (float4*)out;
        float4 z = make_float4(0.0f, 0.0f, 0.0f, 0.0f);
        int base = zb * 512 + threadIdx.x;
        o4[base] = z;
        o4[base + 256] = z;
    }
}

// block-local scale from the 64 partials (identical fp32 op sequence everywhere)
__device__ __forceinline__ float block_scale(const float* pmin, const float* pmax,
                                             float* sca_lds) {
    int t = threadIdx.x;
    if (t < 64) {
        float vmin = pmin[t];
        float vmax = pmax[t];
        #pragma unroll
        for (int off = 32; off > 0; off >>= 1) {
            vmin = fminf(vmin, __shfl_down(vmin, off, 64));
            vmax = fmaxf(vmax, __shfl_down(vmax, off, 64));
        }
        if (t == 0) {
            float tt = __fadd_rn(__fsub_rn(vmax, vmin), 1e-9f);
            *sca_lds = __fdiv_rn(15.0f, tt);
        }
    }
    __syncthreads();
    return *sca_lds;
}

// ---------------- prep: quantize weights into MFMA A-fragment order ----------------
// slot = ((g*18 + r)*8 + mt*2 + khalf)*64 + lane ; 16B per slot (8 bf16, k ascending)
// value(lane, j) = wq[d = 64r + khalf*32 + (lane>>4)*8 + j][m = g*64 + mt*16 + (lane&15)]
__global__ __launch_bounds__(256) void k_quantb(const float* __restrict__ w,
                                                const float* __restrict__ pmin,
                                                const float* __restrict__ pmax,
                                                uv4* __restrict__ wqb) {
    __shared__ float sca;
    float s = block_scale(pmin, pmax, &sca);
    int slot = blockIdx.x * 256 + threadIdx.x;   // 36864 total
    int lane = slot & 63;
    int sub = slot >> 6;
    int khalf = sub & 1;
    int mt = (sub >> 1) & 3;
    int gr = sub >> 3;                 // g*18 + r
    int g = gr / 18, r = gr - g * 18;
    int m = g * 64 + mt * 16 + (lane & 15);
    int dbase = r * 64 + khalf * 32 + (lane >> 4) * 8;
    const float* wp = w + (size_t)m * 1152 + dbase;
    unsigned o[4];
    #pragma unroll
    for (int p = 0; p < 4; ++p) {
        float q0 = rintf(__fmul_rn(wp[2 * p], s));
        float q1 = rintf(__fmul_rn(wp[2 * p + 1], s));
        q0 = fminf(fmaxf(q0, -7.0f), 7.0f);
        q1 = fminf(fmaxf(q1, -7.0f), 7.0f);
        o[p] = (unsigned)bf16rn(q0) | ((unsigned)bf16rn(q1) << 16);
    }
    uv4 v; v.x = o[0]; v.y = o[1]; v.z = o[2]; v.w = o[3];
    wqb[slot] = v;
}

// issue the 16 B-gather u32 loads for chunk rr into dst[16]
// (offsets via 4x ds_read_b128; q2<8 -> khalf0, q2>=8 -> khalf1)
#define ISSUE_B(rr, dst) do {                                                  \
    const int4* _oa = reinterpret_cast<const int4*>(&ofs_s[(rr) * 64 + quad * 8]); \
    int4 _o0 = _oa[0], _o1 = _oa[1];                                           \
    const int4* _ob = reinterpret_cast<const int4*>(&ofs_s[(rr) * 64 + 32 + quad * 8]); \
    int4 _o2 = _ob[0], _o3 = _ob[1];                                           \
    dst[0] = xw[_o0.x]; dst[1] = xw[_o0.y]; dst[2] = xw[_o0.z]; dst[3] = xw[_o0.w]; \
    dst[4] = xw[_o1.x]; dst[5] = xw[_o1.y]; dst[6] = xw[_o1.z]; dst[7] = xw[_o1.w]; \
    dst[8] = xw[_o2.x]; dst[9] = xw[_o2.y]; dst[10] = xw[_o2.z]; dst[11] = xw[_o2.w]; \
    dst[12] = xw[_o3.x]; dst[13] = xw[_o3.y]; dst[14] = xw[_o3.z]; dst[15] = xw[_o3.w]; \
} while (0)

// ---------------- main: split-K gather GEMM + A/B prefetch + in-block fix ----------------
__global__ __launch_bounds__(256, 6) void k_main(const unsigned* __restrict__ xpk,
                                                 const uv4* __restrict__ wqb,
                                                 const float* __restrict__ inp,
                                                 const float* __restrict__ weight,
                                                 const float* __restrict__ pmin,
                                                 const float* __restrict__ pmax,
                                                 float* __restrict__ out) {
    __shared__ alignas(16) int ofs_s[1152]; // plane offset for each k: cin*1156+kh*34+kw
    __shared__ unsigned hitbuf[HITCAP];
    __shared__ unsigned hitcnt;
    __shared__ float sca;

    const int t = threadIdx.x;
    if (t == 0) hitcnt = 0u;
    float sc = block_scale(pmin, pmax, &sca);   // also covers the hitcnt init barrier
    for (int k = t; k < 1152; k += 256) {
        int cin = k / 9;
        int rem = k - cin * 9;
        int kh = rem / 3;
        int kw = rem - kh * 3;
        ofs_s[k] = cin * 1156 + kh * 34 + kw;
    }
    __syncthreads();

    const int lane = t & 63;
    const int wv = t >> 6;             // wave id = n-tile
    const int quad = lane >> 4;
    const int nl = lane & 15;
    const int n0 = blockIdx.x * 64;
    const int g = blockIdx.y;
    const int kz = blockIdx.z;         // split-K half: chunks [kz*9, kz*9+9)
    const int r0 = kz * 9, rend = r0 + 9;
    const int b = n0 >> 10;

    // wave's image-position base (16 consecutive positions within one row)
    const int sy_w = ((n0 & 1023) >> 5) + (wv >> 1);
    const int col0 = (wv & 1) * 16;
    const unsigned* __restrict__ xw =
        xpk + (size_t)b * (128 * 1156) + sy_w * 34 + col0 + nl;
    const uv4* __restrict__ aw = wqb + (size_t)g * (18 * 512) + lane;

    int counts[4][4] = {};

    // ---- prologue: prefetch chunk r0's B-gather u32s and (r0, mt0) A-frags ----
    unsigned pb[16];
    ISSUE_B(r0, pb);
    short8 ac0 = __builtin_bit_cast(short8, aw[r0 * 512]);
    short8 ac1 = __builtin_bit_cast(short8, aw[r0 * 512 + 64]);

    for (int r = r0; r < rend; ++r) {
        // consume prefetched B, issue next chunk's gathers immediately
        unsigned cb[16];
        #pragma unroll
        for (int q2 = 0; q2 < 16; ++q2) cb[q2] = pb[q2];
        if (r + 1 < rend) ISSUE_B(r + 1, pb);

        // ---- repack current B (split packed hi|lo) via v_perm_b32 ----
        short8 bhi[2], blo[2];
        #pragma unroll
        for (int kh2 = 0; kh2 < 2; ++kh2) {
            union { unsigned d[4]; short8 v; } H, L;
            #pragma unroll
            for (int p = 0; p < 4; ++p) {
                unsigned ua = cb[kh2 * 8 + 2 * p], ub = cb[kh2 * 8 + 2 * p + 1];
                H.d[p] = __builtin_amdgcn_perm(ub, ua, 0x05040100u); // ua.lo | ub.lo<<16
                L.d[p] = __builtin_amdgcn_perm(ub, ua, 0x07060302u); // ua.hi | ub.hi<<16
            }
            bhi[kh2] = H.v;
            blo[kh2] = L.v;
        }

        // ---- per m-tile: rolling depth-1 A prefetch, 4 MFMAs, checks ----
        #pragma unroll
        for (int mt = 0; mt < 4; ++mt) {
            // prefetch next pair of A-frags (next mt, or next r's mt0; the very
            // last prefetch wraps to r0 -- dummy but valid/L1-hot, keeps it branchless)
            int pn = (mt == 3) ? (((r + 1) < rend ? (r + 1) : r0) * 512)
                               : (r * 512 + (mt + 1) * 128);
            short8 an0 = __builtin_bit_cast(short8, aw[pn]);
            short8 an1 = __builtin_bit_cast(short8, aw[pn + 64]);

            f32x4 acc = {0.0f, 0.0f, 0.0f, 0.0f};
            acc = __builtin_amdgcn_mfma_f32_16x16x32_bf16(ac0, bhi[0], acc, 0, 0, 0);
            acc = __builtin_amdgcn_mfma_f32_16x16x32_bf16(ac1, bhi[1], acc, 0, 0, 0);
            acc = __builtin_amdgcn_mfma_f32_16x16x32_bf16(ac0, blo[0], acc, 0, 0, 0);
            acc = __builtin_amdgcn_mfma_f32_16x16x32_bf16(ac1, blo[1], acc, 0, 0, 0);
            #pragma unroll
            for (int i = 0; i < 4; ++i) {
                float s = acc[i];
                int ge = (s >= 0.0f) ? 1 : 0;
                counts[mt][i] += ge;
                if (__builtin_fabsf(s) < TAU) {
                    unsigned idx = atomicAdd(&hitcnt, 1u);   // LDS atomic: fast, rare
                    if (idx < (unsigned)HITCAP) {
                        unsigned m = (unsigned)(g * 64 + mt * 16 + quad * 4 + i);
                        unsigned n = (unsigned)(n0 + wv * 16 + nl);
                        hitbuf[idx] = n | ((unsigned)r << 14) | (m << 19) | ((unsigned)ge << 27);
                    }
                }
            }
            ac0 = an0;
            ac1 = an1;
        }
    }

    // ---- epilogue: C/D layout col=lane&15 (n), row=quad*4+reg (m) ----
    // split-K: accumulate into pre-zeroed out (integer-valued f32 adds: exact)
    {
        const int n = n0 + wv * 16 + nl;
        const int p = n & 1023;
        #pragma unroll
        for (int mt = 0; mt < 4; ++mt)
            #pragma unroll
            for (int i = 0; i < 4; ++i) {
                int m = g * 64 + mt * 16 + quad * 4 + i;
                atomicAdd(&out[(((size_t)(b * 256 + m)) << 10) + p],
                          (float)counts[mt][i]);
            }
    }

    // ---- in-block fixup of this block's own hits (R4 k_fix body, verbatim math) ----
    __syncthreads();
    unsigned tot = hitcnt;
    if (tot > (unsigned)HITCAP) tot = (unsigned)HITCAP;
    for (unsigned i = t; i < tot; i += 256) {
        unsigned u = hitbuf[i];
        int n = u & 16383;
        int r = (u >> 14) & 31;
        int m = (u >> 19) & 255;
        int bit = (u >> 27) & 1;
        int bb = n >> 10, p = n & 1023, y = p >> 5, x = p & 31;
        const float* ib = inp + (size_t)bb * (128 * 32 * 32);
        const float* wp = weight + (size_t)m * 1152;
        float s = 0.0f;
        int d = r * 64;
        for (int c = 0; c < 64; ++c, ++d) {
            int ci = d / 9, rem = d - ci * 9;
            int kh = rem / 3, kw = rem - kh * 3;
            int yy = y + kh - 1, xx = x + kw - 1;
            float xv = 0.0f;
            if ((unsigned)yy < 32u && (unsigned)xx < 32u)
                xv = ib[(ci * 32 + yy) * 32 + xx];
            float q = rintf(__fmul_rn(wp[d], sc));
            q = fminf(fmaxf(q, -7.0f), 7.0f);
            s = __fadd_rn(s, __fmul_rn(xv, q));
        }
        int nb = (s >= 0.0f) ? 1 : 0;
        if (nb != bit)
            atomicAdd(&out[(((size_t)(bb * 256 + m)) << 10) + p], nb ? 1.0f : -1.0f);
    }
}

extern "C" void kernel_launch(void* const* d_in, const int* in_sizes, int n_in,
                              void* d_out, int out_size, void* d_ws, size_t ws_size,
                              hipStream_t stream) {
    const float* inp    = (const float*)d_in[0];   // [16,128,32,32]
    const float* weight = (const float*)d_in[1];   // [256,128,3,3]
    float* out = (float*)d_out;                    // [16,256,32,32]

    char* ws = (char*)d_ws;
    float*    pmin  = (float*)(ws + 0);
    float*    pmax  = (float*)(ws + 256);
    uv4*      wqb   = (uv4*)(ws + 1024);          // 589,824 B
    unsigned* xpk   = (unsigned*)(ws + 590848);   // 9,469,952 B

    k_prep<<<4160, 256, 0, stream>>>(weight, inp, pmin, pmax, xpk, out);
    k_quantb<<<144, 256, 0, stream>>>(weight, pmin, pmax, wqb);

    dim3 grid(256, 4, 2);   // (N/64, M/64, split-K)
    k_main<<<grid, 256, 0, stream>>>(xpk, wqb, inp, weight, pmin, pmax, out);
}

// Round 2
// 127.795 us; speedup vs baseline: 1.3259x; 1.3259x over previous
//
#include <hip/hip_runtime.h>

// ONN conv2d: B=16, Cin=128, H=W=32, Cout=256, k=3 (pad=1, stride=1)
// N=16384 positions, D=1152=18*64 chunks of VEC=64, M=256.
// out[n,m] = sum_r sign01( dot_c( x[n,64r+c], wq[64r+c,m] ) )
// wq = clamp(rintf(w*scale), -7, 7), scale = fl32(15/(fl32(max-min)+1e-9f))
//
// Main path: bf16 MFMA with x split hi/lo (w int4 exact in bf16).
// |mfma_dot - ref_fp32_chain| < ~2e-3; dots with |s| < TAU=0.03 recomputed
// bit-exactly (sequential fp32, ascending c, separate mul/add -- R4 body).
// R3->R4: per-dot global atomics -> per-block LDS queue (611 -> 93 us).
// R5 FAILED: rewritten k_fix body flipped a sign; reverted (proven R4 body).
// R6: k_fix grid 64->512. R7: barrier-free gather k_main.
// R8: depth-1 B prefetch + k_fix folded into k_main tail (64 us k_main;
//     MfmaUtil 11.5 / VALUBusy 41.6 / Occ 30, VGPR 56 -- 47% idle-stall).
// R9 FAILED (101 us k_main): split-K atomicAdd epilogue blew HBM traffic
//     (WRITE 16.5->105 MB, 150 MB total = HBM-bound) and launch_bounds(256,6)
//     squeezed VGPR to 40, defeating all prefetch (VALUBusy fell to 28).
// R10: revert to R8 grid/stores. Root cause of idle-stall: the per-dot
//     |s|<TAU branch made 64 BBs/chunk; AMDGPU scheduler won't hoist VMEM
//     across BBs, so R8's "prefetch" loads sank to use (hence VGPR=56).
//     Now: branchless hot chunk (one BB): 16 MFMAs, hit bits -> per-lane
//     mask, accs kept live; ONE rare per-chunk cold handler (same encode,
//     same LDS queue, same R4 fix body). Rolling A-pair prefetch,
//     branchless B prefetch (clamped rn), b128 offset reads, v_perm repack,
//     byte offsets in ofs_s.

#define TAU 0.03f
#define HITCAP 2048

typedef short short8 __attribute__((ext_vector_type(8)));
typedef float f32x4 __attribute__((ext_vector_type(4)));
typedef unsigned int uv4 __attribute__((ext_vector_type(4)));

__device__ __forceinline__ unsigned short bf16rn(float v) {
    unsigned u = __float_as_uint(v);
    unsigned r = u + 0x7fffu + ((u >> 16) & 1u);
    return (unsigned short)(r >> 16);
}

// ---------------- prep: weight min/max partials (blocks 0..63) +
//                  zero-padded hi/lo bf16 planes (blocks 64..2111) ----------------
__global__ __launch_bounds__(256) void k_prep(const float* __restrict__ w,
                                              const float* __restrict__ inp,
                                              float* __restrict__ pmin,
                                              float* __restrict__ pmax,
                                              unsigned* __restrict__ xpk) {
    if (blockIdx.x < 64) {
        int tid = blockIdx.x * 256 + threadIdx.x;
        float vmin = 1e30f, vmax = -1e30f;
        for (int i = tid; i < 294912; i += 64 * 256) {
            float v = w[i];
            vmin = fminf(vmin, v);
            vmax = fmaxf(vmax, v);
        }
        #pragma unroll
        for (int off = 32; off > 0; off >>= 1) {
            vmin = fminf(vmin, __shfl_down(vmin, off, 64));
            vmax = fmaxf(vmax, __shfl_down(vmax, off, 64));
        }
        __shared__ float smin[4], smax[4];
        int wave = threadIdx.x >> 6;
        if ((threadIdx.x & 63) == 0) { smin[wave] = vmin; smax[wave] = vmax; }
        __syncthreads();
        if (threadIdx.x == 0) {
            #pragma unroll
            for (int i = 1; i < 4; i++) {
                vmin = fminf(vmin, smin[i]);
                vmax = fmaxf(vmax, smax[i]);
            }
            pmin[blockIdx.x] = vmin;
            pmax[blockIdx.x] = vmax;
        }
    } else {
        int bc = blockIdx.x - 64;              // b*128 + cin (2048)
        const float* src = inp + (size_t)bc * 1024;
        unsigned* dst = xpk + (size_t)bc * 1156;
        #pragma unroll
        for (int i = 0; i < 5; ++i) {
            int idx = threadIdx.x + i * 256;
            if (idx < 1156) {
                int yy = idx / 34, xx = idx - yy * 34;
                float v = 0.0f;
                int ys = yy - 1, xs_ = xx - 1;
                if ((unsigned)ys < 32u && (unsigned)xs_ < 32u) v = src[ys * 32 + xs_];
                unsigned short h = bf16rn(v);
                float hf = __uint_as_float((unsigned)h << 16);
                unsigned short l = bf16rn(v - hf);
                dst[idx] = (unsigned)h | ((unsigned)l << 16);
            }
        }
    }
}

// block-local scale from the 64 partials (identical fp32 op sequence everywhere)
__device__ __forceinline__ float block_scale(const float* pmin, const float* pmax,
                                             float* sca_lds) {
    int t = threadIdx.x;
    if (t < 64) {
        float vmin = pmin[t];
        float vmax = pmax[t];
        #pragma unroll
        for (int off = 32; off > 0; off >>= 1) {
            vmin = fminf(vmin, __shfl_down(vmin, off, 64));
            vmax = fmaxf(vmax, __shfl_down(vmax, off, 64));
        }
        if (t == 0) {
            float tt = __fadd_rn(__fsub_rn(vmax, vmin), 1e-9f);
            *sca_lds = __fdiv_rn(15.0f, tt);
        }
    }
    __syncthreads();
    return *sca_lds;
}

// ---------------- prep: quantize weights into MFMA A-fragment order ----------------
// slot = ((g*18 + r)*8 + mt*2 + khalf)*64 + lane ; 16B per slot (8 bf16, k ascending)
// value(lane, j) = wq[d = 64r + khalf*32 + (lane>>4)*8 + j][m = g*64 + mt*16 + (lane&15)]
__global__ __launch_bounds__(256) void k_quantb(const float* __restrict__ w,
                                                const float* __restrict__ pmin,
                                                const float* __restrict__ pmax,
                                                uv4* __restrict__ wqb) {
    __shared__ float sca;
    float s = block_scale(pmin, pmax, &sca);
    int slot = blockIdx.x * 256 + threadIdx.x;   // 36864 total
    int lane = slot & 63;
    int sub = slot >> 6;
    int khalf = sub & 1;
    int mt = (sub >> 1) & 3;
    int gr = sub >> 3;                 // g*18 + r
    int g = gr / 18, r = gr - g * 18;
    int m = g * 64 + mt * 16 + (lane & 15);
    int dbase = r * 64 + khalf * 32 + (lane >> 4) * 8;
    const float* wp = w + (size_t)m * 1152 + dbase;
    unsigned o[4];
    #pragma unroll
    for (int p = 0; p < 4; ++p) {
        float q0 = rintf(__fmul_rn(wp[2 * p], s));
        float q1 = rintf(__fmul_rn(wp[2 * p + 1], s));
        q0 = fminf(fmaxf(q0, -7.0f), 7.0f);
        q1 = fminf(fmaxf(q1, -7.0f), 7.0f);
        o[p] = (unsigned)bf16rn(q0) | ((unsigned)bf16rn(q1) << 16);
    }
    uv4 v; v.x = o[0]; v.y = o[1]; v.z = o[2]; v.w = o[3];
    wqb[slot] = v;
}

// byte-offset gather load
#define XLD(o) (*reinterpret_cast<const unsigned*>(xwB + (o)))

// issue the 16 B-gather u32 loads for chunk rr into dst[16]
// (byte offsets via 4x ds_read_b128; q2<8 -> khalf0, q2>=8 -> khalf1)
#define ISSUE_B(rr, dst) do {                                                  \
    const int4* _oa = reinterpret_cast<const int4*>(&ofs_s[(rr) * 64 + quad * 8]); \
    int4 _o0 = _oa[0], _o1 = _oa[1];                                           \
    const int4* _ob = reinterpret_cast<const int4*>(&ofs_s[(rr) * 64 + 32 + quad * 8]); \
    int4 _o2 = _ob[0], _o3 = _ob[1];                                           \
    dst[0] = XLD(_o0.x); dst[1] = XLD(_o0.y); dst[2] = XLD(_o0.z); dst[3] = XLD(_o0.w); \
    dst[4] = XLD(_o1.x); dst[5] = XLD(_o1.y); dst[6] = XLD(_o1.z); dst[7] = XLD(_o1.w); \
    dst[8] = XLD(_o2.x); dst[9] = XLD(_o2.y); dst[10] = XLD(_o2.z); dst[11] = XLD(_o2.w); \
    dst[12] = XLD(_o3.x); dst[13] = XLD(_o3.y); dst[14] = XLD(_o3.z); dst[15] = XLD(_o3.w); \
} while (0)

// ---------------- main: single-BB gather GEMM + A/B prefetch + in-block fix ----------------
__global__ __launch_bounds__(256) void k_main(const unsigned* __restrict__ xpk,
                                              const uv4* __restrict__ wqb,
                                              const float* __restrict__ inp,
                                              const float* __restrict__ weight,
                                              const float* __restrict__ pmin,
                                              const float* __restrict__ pmax,
                                              float* __restrict__ out) {
    __shared__ alignas(16) int ofs_s[1152]; // BYTE plane offset per k: (cin*1156+kh*34+kw)*4
    __shared__ unsigned hitbuf[HITCAP];
    __shared__ unsigned hitcnt;
    __shared__ float sca;

    const int t = threadIdx.x;
    if (t == 0) hitcnt = 0u;
    float sc = block_scale(pmin, pmax, &sca);   // also covers the hitcnt init barrier
    for (int k = t; k < 1152; k += 256) {
        int cin = k / 9;
        int rem = k - cin * 9;
        int kh = rem / 3;
        int kw = rem - kh * 3;
        ofs_s[k] = (cin * 1156 + kh * 34 + kw) * 4;
    }
    __syncthreads();

    const int lane = t & 63;
    const int wv = t >> 6;             // wave id = n-tile
    const int quad = lane >> 4;
    const int nl = lane & 15;
    const int n0 = blockIdx.x * 64;
    const int g = blockIdx.y;
    const int b = n0 >> 10;

    // wave's image-position base (16 consecutive positions within one row)
    const int sy_w = ((n0 & 1023) >> 5) + (wv >> 1);
    const int col0 = (wv & 1) * 16;
    const unsigned* __restrict__ xw =
        xpk + (size_t)b * (128 * 1156) + sy_w * 34 + col0 + nl;
    const char* __restrict__ xwB = (const char*)xw;
    const uv4* __restrict__ aw = wqb + (size_t)g * (18 * 512) + lane;

    int counts[4][4] = {};

    // ---- prologue: prefetch chunk 0's B-gather u32s and (0, mt0) A-frags ----
    unsigned pb[16];
    ISSUE_B(0, pb);
    short8 ac0 = __builtin_bit_cast(short8, aw[0]);
    short8 ac1 = __builtin_bit_cast(short8, aw[64]);

    for (int r = 0; r < 18; ++r) {
        // ---- repack current B (split packed hi|lo) via v_perm_b32 ----
        short8 bhi[2], blo[2];
        #pragma unroll
        for (int kh2 = 0; kh2 < 2; ++kh2) {
            union { unsigned d[4]; short8 v; } H, L;
            #pragma unroll
            for (int p = 0; p < 4; ++p) {
                unsigned ua = pb[kh2 * 8 + 2 * p], ub = pb[kh2 * 8 + 2 * p + 1];
                H.d[p] = __builtin_amdgcn_perm(ub, ua, 0x05040100u); // ua.lo | ub.lo<<16
                L.d[p] = __builtin_amdgcn_perm(ub, ua, 0x07060302u); // ua.hi | ub.hi<<16
            }
            bhi[kh2] = H.v;
            blo[kh2] = L.v;
        }

        // issue next chunk's gathers, branchless (r=17 harmlessly reloads 17)
        const int rn = (r < 17) ? r + 1 : 17;
        ISSUE_B(rn, pb);

        // ---- 4 m-tiles, fully branchless; rolling depth-1 A-pair prefetch ----
        f32x4 accs[4];
        unsigned hm = 0u;              // per-lane hit mask over (mt,i)
        #pragma unroll
        for (int mt = 0; mt < 4; ++mt) {
            const int pn = (mt == 3) ? rn * 512 : (r * 512 + (mt + 1) * 128);
            short8 an0 = __builtin_bit_cast(short8, aw[pn]);
            short8 an1 = __builtin_bit_cast(short8, aw[pn + 64]);

            f32x4 acc = {0.0f, 0.0f, 0.0f, 0.0f};
            acc = __builtin_amdgcn_mfma_f32_16x16x32_bf16(ac0, bhi[0], acc, 0, 0, 0);
            acc = __builtin_amdgcn_mfma_f32_16x16x32_bf16(ac1, bhi[1], acc, 0, 0, 0);
            acc = __builtin_amdgcn_mfma_f32_16x16x32_bf16(ac0, blo[0], acc, 0, 0, 0);
            acc = __builtin_amdgcn_mfma_f32_16x16x32_bf16(ac1, blo[1], acc, 0, 0, 0);
            accs[mt] = acc;
            #pragma unroll
            for (int i = 0; i < 4; ++i) {
                float s = acc[i];
                counts[mt][i] += (s >= 0.0f) ? 1 : 0;
                hm |= (__builtin_fabsf(s) < TAU ? 1u : 0u) << (mt * 4 + i);
            }
            ac0 = an0;
            ac1 = an1;
        }

        // ---- one rare cold branch per chunk: queue hits (same encode as R8) ----
        if (__any((int)hm)) {
            #pragma unroll
            for (int mt = 0; mt < 4; ++mt)
                #pragma unroll
                for (int i = 0; i < 4; ++i)
                    if (hm & (1u << (mt * 4 + i))) {
                        float s = accs[mt][i];
                        int ge = (s >= 0.0f) ? 1 : 0;
                        unsigned idx = atomicAdd(&hitcnt, 1u);   // LDS atomic: rare
                        if (idx < (unsigned)HITCAP) {
                            unsigned m = (unsigned)(g * 64 + mt * 16 + quad * 4 + i);
                            unsigned n = (unsigned)(n0 + wv * 16 + nl);
                            hitbuf[idx] = n | ((unsigned)r << 14) | (m << 19)
                                            | ((unsigned)ge << 27);
                        }
                    }
        }
    }

    // ---- epilogue: C/D layout col=lane&15 (n), row=quad*4+reg (m) ----
    {
        const int n = n0 + wv * 16 + nl;
        const int p = n & 1023;
        #pragma unroll
        for (int mt = 0; mt < 4; ++mt)
            #pragma unroll
            for (int i = 0; i < 4; ++i) {
                int m = g * 64 + mt * 16 + quad * 4 + i;
                out[(((size_t)(b * 256 + m)) << 10) + p] = (float)counts[mt][i];
            }
    }

    // ---- in-block fixup of this block's own hits (R4 k_fix body, verbatim math) ----
    __syncthreads();
    unsigned tot = hitcnt;
    if (tot > (unsigned)HITCAP) tot = (unsigned)HITCAP;
    for (unsigned i = t; i < tot; i += 256) {
        unsigned u = hitbuf[i];
        int n = u & 16383;
        int r = (u >> 14) & 31;
        int m = (u >> 19) & 255;
        int bit = (u >> 27) & 1;
        int bb = n >> 10, p = n & 1023, y = p >> 5, x = p & 31;
        const float* ib = inp + (size_t)bb * (128 * 32 * 32);
        const float* wp = weight + (size_t)m * 1152;
        float s = 0.0f;
        int d = r * 64;
        for (int c = 0; c < 64; ++c, ++d) {
            int ci = d / 9, rem = d - ci * 9;
            int kh = rem / 3, kw = rem - kh * 3;
            int yy = y + kh - 1, xx = x + kw - 1;
            float xv = 0.0f;
            if ((unsigned)yy < 32u && (unsigned)xx < 32u)
                xv = ib[(ci * 32 + yy) * 32 + xx];
            float q = rintf(__fmul_rn(wp[d], sc));
            q = fminf(fmaxf(q, -7.0f), 7.0f);
            s = __fadd_rn(s, __fmul_rn(xv, q));
        }
        int nb = (s >= 0.0f) ? 1 : 0;
        if (nb != bit)
            atomicAdd(&out[(((size_t)(bb * 256 + m)) << 10) + p], nb ? 1.0f : -1.0f);
    }
}

extern "C" void kernel_launch(void* const* d_in, const int* in_sizes, int n_in,
                              void* d_out, int out_size, void* d_ws, size_t ws_size,
                              hipStream_t stream) {
    const float* inp    = (const float*)d_in[0];   // [16,128,32,32]
    const float* weight = (const float*)d_in[1];   // [256,128,3,3]
    float* out = (float*)d_out;                    // [16,256,32,32]

    char* ws = (char*)d_ws;
    float*    pmin  = (float*)(ws + 0);
    float*    pmax  = (float*)(ws + 256);
    uv4*      wqb   = (uv4*)(ws + 1024);          // 589,824 B
    unsigned* xpk   = (unsigned*)(ws + 590848);   // 9,469,952 B

    k_prep<<<2112, 256, 0, stream>>>(weight, inp, pmin, pmax, xpk);
    k_quantb<<<144, 256, 0, stream>>>(weight, pmin, pmax, wqb);

    dim3 grid(256, 4);   // (N/64, M/64)
    k_main<<<grid, 256, 0, stream>>>(xpk, wqb, inp, weight, pmin, pmax, out);
}

// Round 3
// 124.248 us; speedup vs baseline: 1.3638x; 1.0285x over previous
//
#include <hip/hip_runtime.h>

// ONN conv2d: B=16, Cin=128, H=W=32, Cout=256, k=3 (pad=1, stride=1)
// N=16384 positions, D=1152=18*64 chunks of VEC=64, M=256.
// out[n,m] = sum_r sign01( dot_c( x[n,64r+c], wq[64r+c,m] ) )
// wq = clamp(rintf(w*scale), -7, 7), scale = fl32(15/(fl32(max-min)+1e-9f))
//
// Main path: bf16 MFMA with x split hi/lo (w int4 exact in bf16).
// |mfma_dot - ref_fp32_chain| < ~2e-3; dots with |s| < TAU=0.03 recomputed
// bit-exactly (sequential fp32, ascending c, separate mul/add -- R4 body).
// R3->R4: per-dot global atomics -> per-block LDS queue (611 -> 93 us).
// R5 FAILED: rewritten k_fix body flipped a sign; reverted (proven R4 body).
// R6: k_fix grid 64->512. R7: barrier-free gather k_main.
// R8: depth-1 B prefetch + fix folded into tail (64.3 us k_main).
// R9 FAILED (101 us): split-K atomics blew HBM; launch_bounds squeezed regs.
// R10: branchless hot chunk, one cold handler/chunk (63.0 us; VGPR 64,
//      VALUBusy 47, MfmaUtil 12 -- per-wave fixed machinery dominates).
// R11: amortize fixed costs 2x: 128m per wave (grid 256x2, 8 mt/wave,
//      32 MFMA/chunk/wave, half the waves). Sign VALU 6->3 per element:
//      negcnt += signbit (s>=0 count = 18-negcnt; -0.0 disagreement is
//      |s|<TAU so fixup corrects, ge encoded as !signbit consistently);
//      hit detect = 1 v_cmp via __ballot OR'd into wave-uniform hitacc
//      (SALU), per-lane identity rebuilt in cold block only.
//      Gathers: uniform xpk base + 32-bit byte voffset (1 VALU/gather).

#define TAU 0.03f
#define HITCAP 2048

typedef short short8 __attribute__((ext_vector_type(8)));
typedef float f32x4 __attribute__((ext_vector_type(4)));
typedef unsigned int uv4 __attribute__((ext_vector_type(4)));

__device__ __forceinline__ unsigned short bf16rn(float v) {
    unsigned u = __float_as_uint(v);
    unsigned r = u + 0x7fffu + ((u >> 16) & 1u);
    return (unsigned short)(r >> 16);
}

// ---------------- prep: weight min/max partials (blocks 0..63) +
//                  zero-padded hi/lo bf16 planes (blocks 64..2111) ----------------
__global__ __launch_bounds__(256) void k_prep(const float* __restrict__ w,
                                              const float* __restrict__ inp,
                                              float* __restrict__ pmin,
                                              float* __restrict__ pmax,
                                              unsigned* __restrict__ xpk) {
    if (blockIdx.x < 64) {
        int tid = blockIdx.x * 256 + threadIdx.x;
        float vmin = 1e30f, vmax = -1e30f;
        for (int i = tid; i < 294912; i += 64 * 256) {
            float v = w[i];
            vmin = fminf(vmin, v);
            vmax = fmaxf(vmax, v);
        }
        #pragma unroll
        for (int off = 32; off > 0; off >>= 1) {
            vmin = fminf(vmin, __shfl_down(vmin, off, 64));
            vmax = fmaxf(vmax, __shfl_down(vmax, off, 64));
        }
        __shared__ float smin[4], smax[4];
        int wave = threadIdx.x >> 6;
        if ((threadIdx.x & 63) == 0) { smin[wave] = vmin; smax[wave] = vmax; }
        __syncthreads();
        if (threadIdx.x == 0) {
            #pragma unroll
            for (int i = 1; i < 4; i++) {
                vmin = fminf(vmin, smin[i]);
                vmax = fmaxf(vmax, smax[i]);
            }
            pmin[blockIdx.x] = vmin;
            pmax[blockIdx.x] = vmax;
        }
    } else {
        int bc = blockIdx.x - 64;              // b*128 + cin (2048)
        const float* src = inp + (size_t)bc * 1024;
        unsigned* dst = xpk + (size_t)bc * 1156;
        #pragma unroll
        for (int i = 0; i < 5; ++i) {
            int idx = threadIdx.x + i * 256;
            if (idx < 1156) {
                int yy = idx / 34, xx = idx - yy * 34;
                float v = 0.0f;
                int ys = yy - 1, xs_ = xx - 1;
                if ((unsigned)ys < 32u && (unsigned)xs_ < 32u) v = src[ys * 32 + xs_];
                unsigned short h = bf16rn(v);
                float hf = __uint_as_float((unsigned)h << 16);
                unsigned short l = bf16rn(v - hf);
                dst[idx] = (unsigned)h | ((unsigned)l << 16);
            }
        }
    }
}

// block-local scale from the 64 partials (identical fp32 op sequence everywhere)
__device__ __forceinline__ float block_scale(const float* pmin, const float* pmax,
                                             float* sca_lds) {
    int t = threadIdx.x;
    if (t < 64) {
        float vmin = pmin[t];
        float vmax = pmax[t];
        #pragma unroll
        for (int off = 32; off > 0; off >>= 1) {
            vmin = fminf(vmin, __shfl_down(vmin, off, 64));
            vmax = fmaxf(vmax, __shfl_down(vmax, off, 64));
        }
        if (t == 0) {
            float tt = __fadd_rn(__fsub_rn(vmax, vmin), 1e-9f);
            *sca_lds = __fdiv_rn(15.0f, tt);
        }
    }
    __syncthreads();
    return *sca_lds;
}

// ---------------- prep: quantize weights into MFMA A-fragment order ----------------
// slot = ((g*18 + r)*8 + mt*2 + khalf)*64 + lane ; 16B per slot (8 bf16, k ascending)
// value(lane, j) = wq[d = 64r + khalf*32 + (lane>>4)*8 + j][m = g*64 + mt*16 + (lane&15)]
__global__ __launch_bounds__(256) void k_quantb(const float* __restrict__ w,
                                                const float* __restrict__ pmin,
                                                const float* __restrict__ pmax,
                                                uv4* __restrict__ wqb) {
    __shared__ float sca;
    float s = block_scale(pmin, pmax, &sca);
    int slot = blockIdx.x * 256 + threadIdx.x;   // 36864 total
    int lane = slot & 63;
    int sub = slot >> 6;
    int khalf = sub & 1;
    int mt = (sub >> 1) & 3;
    int gr = sub >> 3;                 // g*18 + r
    int g = gr / 18, r = gr - g * 18;
    int m = g * 64 + mt * 16 + (lane & 15);
    int dbase = r * 64 + khalf * 32 + (lane >> 4) * 8;
    const float* wp = w + (size_t)m * 1152 + dbase;
    unsigned o[4];
    #pragma unroll
    for (int p = 0; p < 4; ++p) {
        float q0 = rintf(__fmul_rn(wp[2 * p], s));
        float q1 = rintf(__fmul_rn(wp[2 * p + 1], s));
        q0 = fminf(fmaxf(q0, -7.0f), 7.0f);
        q1 = fminf(fmaxf(q1, -7.0f), 7.0f);
        o[p] = (unsigned)bf16rn(q0) | ((unsigned)bf16rn(q1) << 16);
    }
    uv4 v; v.x = o[0]; v.y = o[1]; v.z = o[2]; v.w = o[3];
    wqb[slot] = v;
}

// gather: uniform SGPR base + per-lane 32-bit byte offset (xdelta + plane ofs)
#define XLD(o) (*reinterpret_cast<const unsigned*>(xpkB + (xdelta + (unsigned)(o))))

// issue the 16 B-gather u32 loads for chunk rr into dst[16]
// (byte offsets via 4x ds_read_b128; q2<8 -> khalf0, q2>=8 -> khalf1)
#define ISSUE_B(rr, dst) do {                                                  \
    const int4* _oa = reinterpret_cast<const int4*>(&ofs_s[(rr) * 64 + quad * 8]); \
    int4 _o0 = _oa[0], _o1 = _oa[1];                                           \
    const int4* _ob = reinterpret_cast<const int4*>(&ofs_s[(rr) * 64 + 32 + quad * 8]); \
    int4 _o2 = _ob[0], _o3 = _ob[1];                                           \
    dst[0] = XLD(_o0.x); dst[1] = XLD(_o0.y); dst[2] = XLD(_o0.z); dst[3] = XLD(_o0.w); \
    dst[4] = XLD(_o1.x); dst[5] = XLD(_o1.y); dst[6] = XLD(_o1.z); dst[7] = XLD(_o1.w); \
    dst[8] = XLD(_o2.x); dst[9] = XLD(_o2.y); dst[10] = XLD(_o2.z); dst[11] = XLD(_o2.w); \
    dst[12] = XLD(_o3.x); dst[13] = XLD(_o3.y); dst[14] = XLD(_o3.z); dst[15] = XLD(_o3.w); \
} while (0)

// A-fragment slot index for (chunk rr, m-tile mm) at this lane (mm in 0..7;
// wqb layout has 4 original g-groups of 4 mt, our 128m half spans 2 groups)
#define AIDX(rr, mm) ((((mm) >> 2) * 9216) + (rr) * 512 + (((mm) & 3) * 128))

// ---------------- main: 128m/wave gather GEMM + A/B prefetch + in-block fix ----------------
__global__ __launch_bounds__(256) void k_main(const unsigned* __restrict__ xpk,
                                              const uv4* __restrict__ wqb,
                                              const float* __restrict__ inp,
                                              const float* __restrict__ weight,
                                              const float* __restrict__ pmin,
                                              const float* __restrict__ pmax,
                                              float* __restrict__ out) {
    __shared__ alignas(16) int ofs_s[1152]; // BYTE plane offset per k: (cin*1156+kh*34+kw)*4
    __shared__ unsigned hitbuf[HITCAP];
    __shared__ unsigned hitcnt;
    __shared__ float sca;

    const int t = threadIdx.x;
    if (t == 0) hitcnt = 0u;
    float sc = block_scale(pmin, pmax, &sca);   // also covers the hitcnt init barrier
    for (int k = t; k < 1152; k += 256) {
        int cin = k / 9;
        int rem = k - cin * 9;
        int kh = rem / 3;
        int kw = rem - kh * 3;
        ofs_s[k] = (cin * 1156 + kh * 34 + kw) * 4;
    }
    __syncthreads();

    const int lane = t & 63;
    const int wv = t >> 6;             // wave id = n-tile
    const int quad = lane >> 4;
    const int nl = lane & 15;
    const int n0 = blockIdx.x * 64;
    const int g = blockIdx.y;          // 128-m half: m in [g*128, g*128+128)
    const int b = n0 >> 10;

    // wave's image-position base (16 consecutive positions within one row)
    const int sy_w = ((n0 & 1023) >> 5) + (wv >> 1);
    const int col0 = (wv & 1) * 16;
    const char* __restrict__ xpkB = (const char*)xpk;   // uniform base (SGPR)
    const unsigned xdelta =
        ((unsigned)b * (128u * 1156u) + (unsigned)(sy_w * 34 + col0 + nl)) * 4u;
    const uv4* __restrict__ aw = wqb + (size_t)g * (2 * 18 * 512) + lane;

    unsigned negcnt[8][4] = {};
    unsigned long long hitacc = 0ull;

    // ---- prologue: prefetch chunk 0's B-gather u32s and (0, mt0) A-frags ----
    unsigned pb[16];
    ISSUE_B(0, pb);
    short8 ac0 = __builtin_bit_cast(short8, aw[0]);
    short8 ac1 = __builtin_bit_cast(short8, aw[64]);

    for (int r = 0; r < 18; ++r) {
        // ---- repack current B (split packed hi|lo) via v_perm_b32 ----
        short8 bhi[2], blo[2];
        #pragma unroll
        for (int kh2 = 0; kh2 < 2; ++kh2) {
            union { unsigned d[4]; short8 v; } H, L;
            #pragma unroll
            for (int p = 0; p < 4; ++p) {
                unsigned ua = pb[kh2 * 8 + 2 * p], ub = pb[kh2 * 8 + 2 * p + 1];
                H.d[p] = __builtin_amdgcn_perm(ub, ua, 0x05040100u); // ua.lo | ub.lo<<16
                L.d[p] = __builtin_amdgcn_perm(ub, ua, 0x07060302u); // ua.hi | ub.hi<<16
            }
            bhi[kh2] = H.v;
            blo[kh2] = L.v;
        }

        // issue next chunk's gathers, branchless (r=17 harmlessly reloads 17)
        const int rn = (r < 17) ? r + 1 : 17;
        ISSUE_B(rn, pb);

        // ---- 8 m-tiles, fully branchless; rolling depth-1 A-pair prefetch ----
        f32x4 accs[8];
        #pragma unroll
        for (int mt = 0; mt < 8; ++mt) {
            const int pn = (mt == 7) ? AIDX(rn, 0) : AIDX(r, mt + 1);
            short8 an0 = __builtin_bit_cast(short8, aw[pn]);
            short8 an1 = __builtin_bit_cast(short8, aw[pn + 64]);

            f32x4 acc = {0.0f, 0.0f, 0.0f, 0.0f};
            acc = __builtin_amdgcn_mfma_f32_16x16x32_bf16(ac0, bhi[0], acc, 0, 0, 0);
            acc = __builtin_amdgcn_mfma_f32_16x16x32_bf16(ac1, bhi[1], acc, 0, 0, 0);
            acc = __builtin_amdgcn_mfma_f32_16x16x32_bf16(ac0, blo[0], acc, 0, 0, 0);
            acc = __builtin_amdgcn_mfma_f32_16x16x32_bf16(ac1, blo[1], acc, 0, 0, 0);
            accs[mt] = acc;
            #pragma unroll
            for (int i = 0; i < 4; ++i) {
                negcnt[mt][i] += __float_as_uint(acc[i]) >> 31;          // 2 VALU
                hitacc |= __ballot(__builtin_fabsf(acc[i]) < TAU);       // 1 VALU + SALU
            }
            ac0 = an0;
            ac1 = an1;
        }

        // ---- one rare cold branch per chunk: queue hits (per-lane id rebuilt here) ----
        if (hitacc) {
            #pragma unroll
            for (int mt = 0; mt < 8; ++mt)
                #pragma unroll
                for (int i = 0; i < 4; ++i) {
                    float s = accs[mt][i];
                    if (__builtin_fabsf(s) < TAU) {
                        unsigned ge = (__float_as_uint(s) >> 31) ^ 1u;   // match negcnt
                        unsigned idx = atomicAdd(&hitcnt, 1u);           // LDS atomic: rare
                        if (idx < (unsigned)HITCAP) {
                            unsigned m = (unsigned)(g * 128 + mt * 16 + quad * 4 + i);
                            unsigned n = (unsigned)(n0 + wv * 16 + nl);
                            hitbuf[idx] = n | ((unsigned)r << 14) | (m << 19)
                                            | (ge << 27);
                        }
                    }
                }
            hitacc = 0ull;
        }
    }

    // ---- epilogue: C/D layout col=lane&15 (n), row=quad*4+reg (m) ----
    {
        const int n = n0 + wv * 16 + nl;
        const int p = n & 1023;
        #pragma unroll
        for (int mt = 0; mt < 8; ++mt)
            #pragma unroll
            for (int i = 0; i < 4; ++i) {
                int m = g * 128 + mt * 16 + quad * 4 + i;
                out[(((size_t)(b * 256 + m)) << 10) + p] =
                    (float)(18u - negcnt[mt][i]);
            }
    }

    // ---- in-block fixup of this block's own hits (R4 k_fix body, verbatim math) ----
    __syncthreads();
    unsigned tot = hitcnt;
    if (tot > (unsigned)HITCAP) tot = (unsigned)HITCAP;
    for (unsigned i = t; i < tot; i += 256) {
        unsigned u = hitbuf[i];
        int n = u & 16383;
        int r = (u >> 14) & 31;
        int m = (u >> 19) & 255;
        int bit = (u >> 27) & 1;
        int bb = n >> 10, p = n & 1023, y = p >> 5, x = p & 31;
        const float* ib = inp + (size_t)bb * (128 * 32 * 32);
        const float* wp = weight + (size_t)m * 1152;
        float s = 0.0f;
        int d = r * 64;
        for (int c = 0; c < 64; ++c, ++d) {
            int ci = d / 9, rem = d - ci * 9;
            int kh = rem / 3, kw = rem - kh * 3;
            int yy = y + kh - 1, xx = x + kw - 1;
            float xv = 0.0f;
            if ((unsigned)yy < 32u && (unsigned)xx < 32u)
                xv = ib[(ci * 32 + yy) * 32 + xx];
            float q = rintf(__fmul_rn(wp[d], sc));
            q = fminf(fmaxf(q, -7.0f), 7.0f);
            s = __fadd_rn(s, __fmul_rn(xv, q));
        }
        int nb = (s >= 0.0f) ? 1 : 0;
        if (nb != bit)
            atomicAdd(&out[(((size_t)(bb * 256 + m)) << 10) + p], nb ? 1.0f : -1.0f);
    }
}

extern "C" void kernel_launch(void* const* d_in, const int* in_sizes, int n_in,
                              void* d_out, int out_size, void* d_ws, size_t ws_size,
                              hipStream_t stream) {
    const float* inp    = (const float*)d_in[0];   // [16,128,32,32]
    const float* weight = (const float*)d_in[1];   // [256,128,3,3]
    float* out = (float*)d_out;                    // [16,256,32,32]

    char* ws = (char*)d_ws;
    float*    pmin  = (float*)(ws + 0);
    float*    pmax  = (float*)(ws + 256);
    uv4*      wqb   = (uv4*)(ws + 1024);          // 589,824 B
    unsigned* xpk   = (unsigned*)(ws + 590848);   // 9,469,952 B

    k_prep<<<2112, 256, 0, stream>>>(weight, inp, pmin, pmax, xpk);
    k_quantb<<<144, 256, 0, stream>>>(weight, pmin, pmax, wqb);

    dim3 grid(256, 2);   // (N/64, M/128)
    k_main<<<grid, 256, 0, stream>>>(xpk, wqb, inp, weight, pmin, pmax, out);
}

// Round 4
// 119.268 us; speedup vs baseline: 1.4207x; 1.0418x over previous
//
#include <hip/hip_runtime.h>

// ONN conv2d: B=16, Cin=128, H=W=32, Cout=256, k=3 (pad=1, stride=1)
// N=16384 positions, D=1152=18*64 chunks of VEC=64, M=256.
// out[n,m] = sum_r sign01( dot_c( x[n,64r+c], wq[64r+c,m] ) )
// wq = clamp(rintf(w*scale), -7, 7), scale = fl32(15/(fl32(max-min)+1e-9f))
//
// Main path: bf16 MFMA with x split hi/lo (w int4 exact in bf16).
// |mfma_dot - ref_fp32_chain| < ~2e-3; dots with |s| < TAU=0.03 recomputed
// bit-exactly (sequential fp32, ascending c, separate mul/add -- R4 body).
// R3->R4: per-dot global atomics -> per-block LDS queue (611 -> 93 us).
// R5 FAILED: rewritten k_fix body flipped a sign; reverted (proven R4 body).
// R6: k_fix grid 64->512. R7: barrier-free gather k_main.
// R8: depth-1 B prefetch + fix folded into tail (64.3 us k_main).
// R9 FAILED (101 us): split-K GLOBAL atomics blew HBM; bounds squeezed regs.
// R10: branchless hot chunk, one cold handler/chunk (63.0 us; VGPR 64).
// R11: 128m/wave amortization + sign-VALU trim. VALUBusy 47->25 (trim
//      worked) but dur 63->73: grid (256,2)=2 blk/CU, ~2 waves/SIMD,
//      65% idle -- latency-bound at depth-1 prefetch.
// R12: keep R11 amortization, restore 4 waves/SIMD: split-K INSIDE the
//      block (512 thr = 4 n-tiles x 2 kz halves, 9 chunks each), merge
//      negcnt via LDS (packed bytes, padded [64][9] to dodge bank
//      conflicts) -- NO global atomics. Total VALU work == R11, half the
//      latency exposure. negcnt packed 2x16-bit per u32 (-16 VGPR, same
//      VALU). launch_bounds(512,4) pins VGPR<=128 (R11 hit 128 naturally).

#define TAU 0.03f
#define HITCAP 2048

typedef short short8 __attribute__((ext_vector_type(8)));
typedef float f32x4 __attribute__((ext_vector_type(4)));
typedef unsigned int uv4 __attribute__((ext_vector_type(4)));

__device__ __forceinline__ unsigned short bf16rn(float v) {
    unsigned u = __float_as_uint(v);
    unsigned r = u + 0x7fffu + ((u >> 16) & 1u);
    return (unsigned short)(r >> 16);
}

// ---------------- prep: weight min/max partials (blocks 0..63) +
//                  zero-padded hi/lo bf16 planes (blocks 64..2111) ----------------
__global__ __launch_bounds__(256) void k_prep(const float* __restrict__ w,
                                              const float* __restrict__ inp,
                                              float* __restrict__ pmin,
                                              float* __restrict__ pmax,
                                              unsigned* __restrict__ xpk) {
    if (blockIdx.x < 64) {
        int tid = blockIdx.x * 256 + threadIdx.x;
        float vmin = 1e30f, vmax = -1e30f;
        for (int i = tid; i < 294912; i += 64 * 256) {
            float v = w[i];
            vmin = fminf(vmin, v);
            vmax = fmaxf(vmax, v);
        }
        #pragma unroll
        for (int off = 32; off > 0; off >>= 1) {
            vmin = fminf(vmin, __shfl_down(vmin, off, 64));
            vmax = fmaxf(vmax, __shfl_down(vmax, off, 64));
        }
        __shared__ float smin[4], smax[4];
        int wave = threadIdx.x >> 6;
        if ((threadIdx.x & 63) == 0) { smin[wave] = vmin; smax[wave] = vmax; }
        __syncthreads();
        if (threadIdx.x == 0) {
            #pragma unroll
            for (int i = 1; i < 4; i++) {
                vmin = fminf(vmin, smin[i]);
                vmax = fmaxf(vmax, smax[i]);
            }
            pmin[blockIdx.x] = vmin;
            pmax[blockIdx.x] = vmax;
        }
    } else {
        int bc = blockIdx.x - 64;              // b*128 + cin (2048)
        const float* src = inp + (size_t)bc * 1024;
        unsigned* dst = xpk + (size_t)bc * 1156;
        #pragma unroll
        for (int i = 0; i < 5; ++i) {
            int idx = threadIdx.x + i * 256;
            if (idx < 1156) {
                int yy = idx / 34, xx = idx - yy * 34;
                float v = 0.0f;
                int ys = yy - 1, xs_ = xx - 1;
                if ((unsigned)ys < 32u && (unsigned)xs_ < 32u) v = src[ys * 32 + xs_];
                unsigned short h = bf16rn(v);
                float hf = __uint_as_float((unsigned)h << 16);
                unsigned short l = bf16rn(v - hf);
                dst[idx] = (unsigned)h | ((unsigned)l << 16);
            }
        }
    }
}

// block-local scale from the 64 partials (identical fp32 op sequence everywhere)
__device__ __forceinline__ float block_scale(const float* pmin, const float* pmax,
                                             float* sca_lds) {
    int t = threadIdx.x;
    if (t < 64) {
        float vmin = pmin[t];
        float vmax = pmax[t];
        #pragma unroll
        for (int off = 32; off > 0; off >>= 1) {
            vmin = fminf(vmin, __shfl_down(vmin, off, 64));
            vmax = fmaxf(vmax, __shfl_down(vmax, off, 64));
        }
        if (t == 0) {
            float tt = __fadd_rn(__fsub_rn(vmax, vmin), 1e-9f);
            *sca_lds = __fdiv_rn(15.0f, tt);
        }
    }
    __syncthreads();
    return *sca_lds;
}

// ---------------- prep: quantize weights into MFMA A-fragment order ----------------
// slot = ((g*18 + r)*8 + mt*2 + khalf)*64 + lane ; 16B per slot (8 bf16, k ascending)
// value(lane, j) = wq[d = 64r + khalf*32 + (lane>>4)*8 + j][m = g*64 + mt*16 + (lane&15)]
__global__ __launch_bounds__(256) void k_quantb(const float* __restrict__ w,
                                                const float* __restrict__ pmin,
                                                const float* __restrict__ pmax,
                                                uv4* __restrict__ wqb) {
    __shared__ float sca;
    float s = block_scale(pmin, pmax, &sca);
    int slot = blockIdx.x * 256 + threadIdx.x;   // 36864 total
    int lane = slot & 63;
    int sub = slot >> 6;
    int khalf = sub & 1;
    int mt = (sub >> 1) & 3;
    int gr = sub >> 3;                 // g*18 + r
    int g = gr / 18, r = gr - g * 18;
    int m = g * 64 + mt * 16 + (lane & 15);
    int dbase = r * 64 + khalf * 32 + (lane >> 4) * 8;
    const float* wp = w + (size_t)m * 1152 + dbase;
    unsigned o[4];
    #pragma unroll
    for (int p = 0; p < 4; ++p) {
        float q0 = rintf(__fmul_rn(wp[2 * p], s));
        float q1 = rintf(__fmul_rn(wp[2 * p + 1], s));
        q0 = fminf(fmaxf(q0, -7.0f), 7.0f);
        q1 = fminf(fmaxf(q1, -7.0f), 7.0f);
        o[p] = (unsigned)bf16rn(q0) | ((unsigned)bf16rn(q1) << 16);
    }
    uv4 v; v.x = o[0]; v.y = o[1]; v.z = o[2]; v.w = o[3];
    wqb[slot] = v;
}

// gather: uniform SGPR base + per-lane 32-bit byte offset (xdelta + plane ofs)
#define XLD(o) (*reinterpret_cast<const unsigned*>(xpkB + (xdelta + (unsigned)(o))))

// issue the 16 B-gather u32 loads for chunk rr into dst[16]
// (byte offsets via 4x ds_read_b128; q2<8 -> khalf0, q2>=8 -> khalf1)
#define ISSUE_B(rr, dst) do {                                                  \
    const int4* _oa = reinterpret_cast<const int4*>(&ofs_s[(rr) * 64 + quad * 8]); \
    int4 _o0 = _oa[0], _o1 = _oa[1];                                           \
    const int4* _ob = reinterpret_cast<const int4*>(&ofs_s[(rr) * 64 + 32 + quad * 8]); \
    int4 _o2 = _ob[0], _o3 = _ob[1];                                           \
    dst[0] = XLD(_o0.x); dst[1] = XLD(_o0.y); dst[2] = XLD(_o0.z); dst[3] = XLD(_o0.w); \
    dst[4] = XLD(_o1.x); dst[5] = XLD(_o1.y); dst[6] = XLD(_o1.z); dst[7] = XLD(_o1.w); \
    dst[8] = XLD(_o2.x); dst[9] = XLD(_o2.y); dst[10] = XLD(_o2.z); dst[11] = XLD(_o2.w); \
    dst[12] = XLD(_o3.x); dst[13] = XLD(_o3.y); dst[14] = XLD(_o3.z); dst[15] = XLD(_o3.w); \
} while (0)

// A-fragment slot index for (chunk rr, m-tile mm) at this lane (mm in 0..7;
// wqb layout has 4 original g-groups of 4 mt, our 128m half spans 2 groups)
#define AIDX(rr, mm) ((((mm) >> 2) * 9216) + (rr) * 512 + (((mm) & 3) * 128))

// ---------------- main: in-block split-K gather GEMM (512 thr) + fix ----------------
// 8 waves = 4 n-tiles x 2 kz halves; each wave: 16n x 128m x 9 chunks.
// kz=1 waves deposit packed negcnt in LDS; kz=0 waves merge + store.
__global__ __launch_bounds__(512, 4) void k_main(const unsigned* __restrict__ xpk,
                                                 const uv4* __restrict__ wqb,
                                                 const float* __restrict__ inp,
                                                 const float* __restrict__ weight,
                                                 const float* __restrict__ pmin,
                                                 const float* __restrict__ pmax,
                                                 float* __restrict__ out) {
    __shared__ alignas(16) int ofs_s[1152]; // BYTE plane offset per k: (cin*1156+kh*34+kw)*4
    __shared__ unsigned hitbuf[HITCAP];
    __shared__ unsigned red_s[4][64][9];    // [nt][lane][mt] packed bytes (+pad col)
    __shared__ unsigned hitcnt;
    __shared__ float sca;

    const int t = threadIdx.x;
    if (t == 0) hitcnt = 0u;
    float sc = block_scale(pmin, pmax, &sca);   // also covers the hitcnt init barrier
    for (int k = t; k < 1152; k += 512) {
        int cin = k / 9;
        int rem = k - cin * 9;
        int kh = rem / 3;
        int kw = rem - kh * 3;
        ofs_s[k] = (cin * 1156 + kh * 34 + kw) * 4;
    }
    __syncthreads();

    const int lane = t & 63;
    const int wv8 = t >> 6;            // 0..7
    const int nt = wv8 >> 1;           // n-tile 0..3
    const int kz = wv8 & 1;            // K half: chunks [kz*9, kz*9+9)
    const int quad = lane >> 4;
    const int nl = lane & 15;
    const int n0 = blockIdx.x * 64;
    const int g = blockIdx.y;          // 128-m half: m in [g*128, g*128+128)
    const int b = n0 >> 10;
    const int r0 = kz * 9, rend = r0 + 9;

    // wave's image-position base (16 consecutive positions within one row)
    const int sy_w = ((n0 & 1023) >> 5) + (nt >> 1);
    const int col0 = (nt & 1) * 16;
    const char* __restrict__ xpkB = (const char*)xpk;   // uniform base (SGPR)
    const unsigned xdelta =
        ((unsigned)b * (128u * 1156u) + (unsigned)(sy_w * 34 + col0 + nl)) * 4u;
    const uv4* __restrict__ aw = wqb + (size_t)g * (2 * 18 * 512) + lane;

    // negcnt packed: [mt][pair] u32, two 16-bit counters (i=2p lo, i=2p+1 hi)
    unsigned negpk[8][2] = {};
    unsigned long long hitacc = 0ull;

    // ---- prologue: prefetch chunk r0's B-gather u32s and (r0, mt0) A-frags ----
    unsigned pb[16];
    ISSUE_B(r0, pb);
    short8 ac0 = __builtin_bit_cast(short8, aw[AIDX(r0, 0)]);
    short8 ac1 = __builtin_bit_cast(short8, aw[AIDX(r0, 0) + 64]);

    for (int r = r0; r < rend; ++r) {
        // ---- repack current B (split packed hi|lo) via v_perm_b32 ----
        short8 bhi[2], blo[2];
        #pragma unroll
        for (int kh2 = 0; kh2 < 2; ++kh2) {
            union { unsigned d[4]; short8 v; } H, L;
            #pragma unroll
            for (int p = 0; p < 4; ++p) {
                unsigned ua = pb[kh2 * 8 + 2 * p], ub = pb[kh2 * 8 + 2 * p + 1];
                H.d[p] = __builtin_amdgcn_perm(ub, ua, 0x05040100u); // ua.lo | ub.lo<<16
                L.d[p] = __builtin_amdgcn_perm(ub, ua, 0x07060302u); // ua.hi | ub.hi<<16
            }
            bhi[kh2] = H.v;
            blo[kh2] = L.v;
        }

        // issue next chunk's gathers, branchless (last r harmlessly reloads)
        const int rn = (r + 1 < rend) ? r + 1 : r;
        ISSUE_B(rn, pb);

        // ---- 8 m-tiles, fully branchless; rolling depth-1 A-pair prefetch ----
        f32x4 accs[8];
        #pragma unroll
        for (int mt = 0; mt < 8; ++mt) {
            const int pn = (mt == 7) ? AIDX(rn, 0) : AIDX(r, mt + 1);
            short8 an0 = __builtin_bit_cast(short8, aw[pn]);
            short8 an1 = __builtin_bit_cast(short8, aw[pn + 64]);

            f32x4 acc = {0.0f, 0.0f, 0.0f, 0.0f};
            acc = __builtin_amdgcn_mfma_f32_16x16x32_bf16(ac0, bhi[0], acc, 0, 0, 0);
            acc = __builtin_amdgcn_mfma_f32_16x16x32_bf16(ac1, bhi[1], acc, 0, 0, 0);
            acc = __builtin_amdgcn_mfma_f32_16x16x32_bf16(ac0, blo[0], acc, 0, 0, 0);
            acc = __builtin_amdgcn_mfma_f32_16x16x32_bf16(ac1, blo[1], acc, 0, 0, 0);
            accs[mt] = acc;
            #pragma unroll
            for (int p = 0; p < 2; ++p) {
                unsigned sb0 = __float_as_uint(acc[2 * p]) >> 31;
                unsigned sb1 = __float_as_uint(acc[2 * p + 1]) >> 31;
                negpk[mt][p] += sb0 + (sb1 << 16);
                hitacc |= __ballot(__builtin_fabsf(acc[2 * p]) < TAU);
                hitacc |= __ballot(__builtin_fabsf(acc[2 * p + 1]) < TAU);
            }
            ac0 = an0;
            ac1 = an1;
        }

        // ---- one rare cold branch per chunk: queue hits (per-lane id rebuilt) ----
        if (hitacc) {
            #pragma unroll
            for (int mt = 0; mt < 8; ++mt)
                #pragma unroll
                for (int i = 0; i < 4; ++i) {
                    float s = accs[mt][i];
                    if (__builtin_fabsf(s) < TAU) {
                        unsigned ge = (__float_as_uint(s) >> 31) ^ 1u;   // match negpk
                        unsigned idx = atomicAdd(&hitcnt, 1u);           // LDS atomic: rare
                        if (idx < (unsigned)HITCAP) {
                            unsigned m = (unsigned)(g * 128 + mt * 16 + quad * 4 + i);
                            unsigned n = (unsigned)(n0 + nt * 16 + nl);
                            hitbuf[idx] = n | ((unsigned)r << 14) | (m << 19)
                                            | (ge << 27);
                        }
                    }
                }
            hitacc = 0ull;
        }
    }

    // ---- merge kz halves via LDS; kz=0 waves store final counts ----
    if (kz == 1) {
        #pragma unroll
        for (int mt = 0; mt < 8; ++mt) {
            unsigned c0 = negpk[mt][0] & 0xffffu, c1 = negpk[mt][0] >> 16;
            unsigned c2 = negpk[mt][1] & 0xffffu, c3 = negpk[mt][1] >> 16;
            red_s[nt][lane][mt] = c0 | (c1 << 8) | (c2 << 16) | (c3 << 24);
        }
    }
    __syncthreads();
    if (kz == 0) {
        const int n = n0 + nt * 16 + nl;
        const int p = n & 1023;
        #pragma unroll
        for (int mt = 0; mt < 8; ++mt) {
            unsigned pk = red_s[nt][lane][mt];
            unsigned tot0 = (negpk[mt][0] & 0xffffu) + (pk & 255u);
            unsigned tot1 = (negpk[mt][0] >> 16) + ((pk >> 8) & 255u);
            unsigned tot2 = (negpk[mt][1] & 0xffffu) + ((pk >> 16) & 255u);
            unsigned tot3 = (negpk[mt][1] >> 16) + (pk >> 24);
            int mb = g * 128 + mt * 16 + quad * 4;
            size_t obase = ((size_t)(b * 256 + mb)) << 10;
            out[obase + p]              = (float)(18u - tot0);
            out[obase + (1ull << 10) + p] = (float)(18u - tot1);
            out[obase + (2ull << 10) + p] = (float)(18u - tot2);
            out[obase + (3ull << 10) + p] = (float)(18u - tot3);
        }
    }

    // ---- in-block fixup of this block's own hits (R4 k_fix body, verbatim math) ----
    __syncthreads();
    unsigned tot = hitcnt;
    if (tot > (unsigned)HITCAP) tot = (unsigned)HITCAP;
    for (unsigned i = t; i < tot; i += 512) {
        unsigned u = hitbuf[i];
        int n = u & 16383;
        int r = (u >> 14) & 31;
        int m = (u >> 19) & 255;
        int bit = (u >> 27) & 1;
        int bb = n >> 10, p = n & 1023, y = p >> 5, x = p & 31;
        const float* ib = inp + (size_t)bb * (128 * 32 * 32);
        const float* wp = weight + (size_t)m * 1152;
        float s = 0.0f;
        int d = r * 64;
        for (int c = 0; c < 64; ++c, ++d) {
            int ci = d / 9, rem = d - ci * 9;
            int kh = rem / 3, kw = rem - kh * 3;
            int yy = y + kh - 1, xx = x + kw - 1;
            float xv = 0.0f;
            if ((unsigned)yy < 32u && (unsigned)xx < 32u)
                xv = ib[(ci * 32 + yy) * 32 + xx];
            float q = rintf(__fmul_rn(wp[d], sc));
            q = fminf(fmaxf(q, -7.0f), 7.0f);
            s = __fadd_rn(s, __fmul_rn(xv, q));
        }
        int nb = (s >= 0.0f) ? 1 : 0;
        if (nb != bit)
            atomicAdd(&out[(((size_t)(bb * 256 + m)) << 10) + p], nb ? 1.0f : -1.0f);
    }
}

extern "C" void kernel_launch(void* const* d_in, const int* in_sizes, int n_in,
                              void* d_out, int out_size, void* d_ws, size_t ws_size,
                              hipStream_t stream) {
    const float* inp    = (const float*)d_in[0];   // [16,128,32,32]
    const float* weight = (const float*)d_in[1];   // [256,128,3,3]
    float* out = (float*)d_out;                    // [16,256,32,32]

    char* ws = (char*)d_ws;
    float*    pmin  = (float*)(ws + 0);
    float*    pmax  = (float*)(ws + 256);
    uv4*      wqb   = (uv4*)(ws + 1024);          // 589,824 B
    unsigned* xpk   = (unsigned*)(ws + 590848);   // 9,469,952 B

    k_prep<<<2112, 256, 0, stream>>>(weight, inp, pmin, pmax, xpk);
    k_quantb<<<144, 256, 0, stream>>>(weight, pmin, pmax, wqb);

    dim3 grid(256, 2);   // (N/64, M/128); 512-thread blocks, split-K in-block
    k_main<<<grid, 512, 0, stream>>>(xpk, wqb, inp, weight, pmin, pmax, out);
}